// Round 9
// baseline (195.836 us; speedup 1.0000x reference)
//
#include <hip/hip_runtime.h>
#include <math.h>

#define B_ROWS 8192
#define C_COLS 32000
#define NBLK   256      // main kernel: 1 block per CU
#define RPB    32       // rows per block
#define NTHR   1024
#define NRED   125      // mdca_reduce blocks (256 cols each)

// ws layout:
// partial fp8 [0, 8192000 bytes)  -- 256 x 32000 e4m3, scaled x512 (8.2 MB)
// ce_blk  f32 at float offset 2048000, 256
// pm      f32 at float offset 2048256, 125
// counter int at float offset 2048384 (reset by fused_main each call)

#define PSCALE   512.0f
#define PRSCALE  (1.0f / 512.0f)

// e4m3 encode, non-negative input, FTZ below 2^-6 (error bound analyzed:
// <= 3e-5 raw per partial -> ~1e-6 on the final scalar). RNE via magic add;
// mantissa carry naturally propagates into the exponent field.
__device__ __forceinline__ unsigned char f2fp8(float f) {
    union { float f; unsigned int u; } v; v.f = f;
    if (f < 0.015625f) return 0;
    const unsigned int u = v.u + 0x7FFFFu + ((v.u >> 20) & 1u);
    const unsigned int e = ((u >> 23) & 0xFFu) - 120u;   // rebias 127->7
    return (unsigned char)((e << 3) | ((u >> 20) & 7u));
}

__device__ __forceinline__ float fp82f(unsigned int b) {  // b = one e4m3 byte
    const unsigned int e = b >> 3, m = b & 7u;
    if (e == 0) return 0.0f;   // we never emit subnormals (FTZ on encode)
    union { unsigned int u; float f; } v;
    v.u = ((e + 120u) << 23) | (m << 20);
    return v.f;
}

// ROUND-8 HOT LOOP VERBATIM (191.1 us, no scratch spill).
// Regression history -- do NOT reintroduce:
//   r3/r4: by-ref-array lambda -> cur/nxt addressable -> scratch, 635/548 us
//   r6:    switch(jo){v=cur[0..7]} runtime select -> scratch, 459 us
// ANY runtime-valued selection among cur[j]/nxt[j] is fatal (rule #20).
// This round changes ONLY the preamble (counter reset) and the flush
// (fp8 encode instead of bf16). Loop body untouched.
__global__ __launch_bounds__(NTHR, 4) void fused_main(const float* __restrict__ logits,
                                                      const int* __restrict__ targets,
                                                      unsigned char* __restrict__ partial,
                                                      float* __restrict__ ce_blk,
                                                      int* __restrict__ counter) {
    __shared__ float colacc[C_COLS];
    __shared__ float zscr[2][16];
    __shared__ float xts[RPB];
    const int tid = threadIdx.x;
    const int blk = blockIdx.x;
    const bool tail = (tid < 832);   // j=7 group covers cols 28672..31999
    const size_t row0 = (size_t)blk * RPB;

    if (blk == 0 && tid == 0) counter[0] = 0;   // arm last-block-done latch
    if (tid < RPB) {
        const int t = targets[row0 + tid];
        xts[tid] = logits[(row0 + tid) * (size_t)C_COLS + t];   // pre-gather x_target
    }
    for (int i = tid; i < C_COLS; i += NTHR) colacc[i] = 0.0f;
    __syncthreads();

    const float* rowbase = logits + row0 * (size_t)C_COLS;

    float4 cur[8], nxt[8];
    cur[7] = make_float4(0.f, 0.f, 0.f, 0.f);
    nxt[7] = make_float4(0.f, 0.f, 0.f, 0.f);
    float ce = 0.0f;

    // load row 0
    {
        const float* p = rowbase;
#pragma unroll
        for (int j = 0; j < 7; ++j)
            cur[j] = *reinterpret_cast<const float4*>(p + j * 4096 + 4 * tid);
        if (tail)
            cur[7] = *reinterpret_cast<const float4*>(p + 28672 + 4 * tid);
    }

    for (int r = 0; r < RPB; ++r) {
        // prefetch next row (hides under exp/reduce/accumulate)
        if (r + 1 < RPB) {
            const float* p = rowbase + (size_t)(r + 1) * C_COLS;
#pragma unroll
            for (int j = 0; j < 7; ++j)
                nxt[j] = *reinterpret_cast<const float4*>(p + j * 4096 + 4 * tid);
            if (tail)
                nxt[7] = *reinterpret_cast<const float4*>(p + 28672 + 4 * tid);
        }

        // in-place exp + thread-local Z
        float z = 0.0f;
#pragma unroll
        for (int j = 0; j < 7; ++j) {
            cur[j].x = __expf(cur[j].x);
            cur[j].y = __expf(cur[j].y);
            cur[j].z = __expf(cur[j].z);
            cur[j].w = __expf(cur[j].w);
            z += (cur[j].x + cur[j].y) + (cur[j].z + cur[j].w);
        }
        if (tail) {
            cur[7].x = __expf(cur[7].x);
            cur[7].y = __expf(cur[7].y);
            cur[7].z = __expf(cur[7].z);
            cur[7].w = __expf(cur[7].w);
            z += (cur[7].x + cur[7].y) + (cur[7].z + cur[7].w);
        }

        // block reduce Z -- SINGLE barrier (parity-buffered wave partials)
#pragma unroll
        for (int off = 1; off < 64; off <<= 1) z += __shfl_xor(z, off);
        if ((tid & 63) == 0) zscr[r & 1][tid >> 6] = z;
        __syncthreads();
        // every wave sums the 16 partials: 1 broadcast LDS read + 4 shuffles
        float zt = zscr[r & 1][tid & 15];
#pragma unroll
        for (int off = 1; off < 16; off <<= 1) zt += __shfl_xor(zt, off);
        const float rz = 1.0f / zt;
        if (tid == 0) ce += __logf(zt) - xts[r];   // CE fused, 1 thread

        // accumulate probs into LDS column accumulator (2-way banks only)
#pragma unroll
        for (int j = 0; j < 7; ++j) {
            const int base = j * 1024 + tid;
            colacc[base]         += cur[j].x * rz;
            colacc[base +  8000] += cur[j].y * rz;
            colacc[base + 16000] += cur[j].z * rz;
            colacc[base + 24000] += cur[j].w * rz;
        }
        if (tail) {
            const int base = 7 * 1024 + tid;
            colacc[base]         += cur[7].x * rz;
            colacc[base +  8000] += cur[7].y * rz;
            colacc[base + 16000] += cur[7].z * rz;
            colacc[base + 24000] += cur[7].w * rz;
        }

        if (r + 1 < RPB) {
#pragma unroll
            for (int j = 0; j < 8; ++j) cur[j] = nxt[j];
        }
    }

    // flush: un-swizzle LDS -> coalesced fp8 (uchar4) stores, scaled x512
    __syncthreads();
    unsigned char* mypart = partial + (size_t)blk * C_COLS;
    for (int c4 = tid; c4 < 8000; c4 += NTHR) {
        uchar4 v;
        v.x = f2fp8(colacc[c4]          * PSCALE);
        v.y = f2fp8(colacc[c4 +  8000]  * PSCALE);
        v.z = f2fp8(colacc[c4 + 16000]  * PSCALE);
        v.w = f2fp8(colacc[c4 + 24000]  * PSCALE);
        *reinterpret_cast<uchar4*>(mypart + 4 * c4) = v;
    }
    if (tid == 0) ce_blk[blk] = ce;
}

// 125 blocks x 1024 threads; block owns 256 columns [c0, c0+256).
// tid = kc*64 + qi: qi = column quad (4 cols via one u32 load), kc = 1 of 16
// k-chunks x 16 partials. LDS histogram of targets replaces global counts.
// The LAST block to finish (device atomic latch) also folds ce_blk + pm into
// the final scalar -- fixed-order sums, bit-deterministic regardless of
// which block executes it.
__global__ __launch_bounds__(NTHR) void mdca_reduce(const unsigned char* __restrict__ partial,
                                                    const int* __restrict__ targets,
                                                    const float* __restrict__ ce_blk,
                                                    float* __restrict__ pm,
                                                    int* __restrict__ counter,
                                                    float* __restrict__ out) {
    __shared__ float4 sred[NTHR];
    __shared__ float sp[16];
    __shared__ int bins[256];
    __shared__ int lastflag;
    const int tid = threadIdx.x;
    const int c0 = blockIdx.x * 256;
    const int qi = tid & 63;
    const int kc = tid >> 6;

    if (tid < 256) bins[tid] = 0;

    // partial sums: 16 u32 loads (64 KB/block, L2/L3-resident)
    const unsigned char* base = partial + c0 + 4 * qi;
    float4 s = make_float4(0.f, 0.f, 0.f, 0.f);
#pragma unroll 4
    for (int i = 0; i < 16; ++i) {
        const int k = kc * 16 + i;
        const unsigned int u =
            *reinterpret_cast<const unsigned int*>(base + (size_t)k * C_COLS);
        s.x += fp82f(u & 0xFFu);
        s.y += fp82f((u >> 8) & 0xFFu);
        s.z += fp82f((u >> 16) & 0xFFu);
        s.w += fp82f((u >> 24) & 0xFFu);
    }
    sred[tid] = s;
    __syncthreads();   // bins zeroed + sred written

    // histogram of targets into this block's 256 bins
    for (int i = tid; i < B_ROWS; i += NTHR) {
        const int t = targets[i] - c0;
        if ((unsigned)t < 256u) atomicAdd(&bins[t], 1);
    }
    __syncthreads();

    float d = 0.0f;
    if (tid < 64) {
        float4 tot = make_float4(0.f, 0.f, 0.f, 0.f);
#pragma unroll
        for (int k2 = 0; k2 < 16; ++k2) {
            const float4 v = sred[k2 * 64 + tid];
            tot.x += v.x; tot.y += v.y; tot.z += v.z; tot.w += v.w;
        }
        const int cl = 4 * tid;
        d = fabsf(tot.x * PRSCALE - (float)bins[cl])
          + fabsf(tot.y * PRSCALE - (float)bins[cl + 1])
          + fabsf(tot.z * PRSCALE - (float)bins[cl + 2])
          + fabsf(tot.w * PRSCALE - (float)bins[cl + 3]);
#pragma unroll
        for (int off = 1; off < 64; off <<= 1) d += __shfl_xor(d, off);
    }
    if (tid == 0) {
        pm[blockIdx.x] = d;
        __threadfence();                          // publish pm before latch
        const int old = atomicAdd(counter, 1);
        lastflag = (old == NRED - 1) ? 1 : 0;
    }
    __syncthreads();

    if (lastflag) {   // block-uniform branch
        __threadfence();                          // acquire: see all pm writes
        const float invB = 1.0f / B_ROWS;
        const float invBC = invB / C_COLS;
        float a = 0.0f;
        if (tid < 256) a = ce_blk[tid] * invB;    // 256 main blocks
        if (tid < NRED) a += pm[tid] * invBC;     // 125 reduce blocks
#pragma unroll
        for (int off = 1; off < 64; off <<= 1) a += __shfl_xor(a, off);
        if ((tid & 63) == 0) sp[tid >> 6] = a;
        __syncthreads();
        if (tid == 0) {
            float t = 0.0f;
#pragma unroll
            for (int w = 0; w < 16; ++w) t += sp[w];
            out[0] = t;
        }
    }
}

extern "C" void kernel_launch(void* const* d_in, const int* in_sizes, int n_in,
                              void* d_out, int out_size, void* d_ws, size_t ws_size,
                              hipStream_t stream) {
    const float* logits = (const float*)d_in[0];
    const int* targets  = (const int*)d_in[1];
    float* ws = (float*)d_ws;
    unsigned char* partial = (unsigned char*)d_ws;   // 256 x 32000 fp8
    float* ce_blk = ws + 2048000;
    float* pm     = ws + 2048256;
    int* counter  = (int*)(ws + 2048384);

    fused_main<<<NBLK, NTHR, 0, stream>>>(logits, targets, partial, ce_blk, counter);
    mdca_reduce<<<NRED, NTHR, 0, stream>>>(partial, targets, ce_blk, pm, counter,
                                           (float*)d_out);
}

// Round 10
// 191.821 us; speedup vs baseline: 1.0209x; 1.0209x over previous
//
#include <hip/hip_runtime.h>
#include <math.h>

#define B_ROWS 8192
#define C_COLS 32000
#define NBLK   256      // main kernel: 1 block per CU
#define RPB    32       // rows per block
#define NTHR   1024

// ws layout:
// partial bf16 [0, 8192000 ushorts)  -- 256 x 32000 bf16 (16.4 MB)
// ce_blk  f32  at float offset 4096000, 256
// pm      f32  at float offset 4096256, 125

__device__ __forceinline__ unsigned short f2bf(float f) {
    union { float f; unsigned int u; } v; v.f = f;
    unsigned int u = v.u;
    u += 0x7FFFu + ((u >> 16) & 1u);   // round-to-nearest-even
    return (unsigned short)(u >> 16);
}

// ROUND-8 SOURCE VERBATIM (191.1 us best; round-9's fp8+latch variant
// regressed to 195.8 -- tail is launch/latency-bound, not traffic-bound).
// Regression history -- do NOT reintroduce:
//   r3/r4: by-ref-array lambda -> cur/nxt addressable -> scratch, 635/548 us
//   r6:    switch(jo){v=cur[0..7]} runtime select -> scratch, 459 us
//   r9:    fp8 partials + last-block-done final fold -> +4.7 us
// ANY runtime-valued selection among cur[j]/nxt[j] is fatal (rule #20).
// Single pass over logits: row in registers, Z via single-barrier block
// reduce (parity-buffered zscr), CE via preamble pre-gather of target
// logits, probs accumulated in a 128 KB LDS column accumulator
// (idx=(c>>2)+(c&3)*8000: 2-way bank aliasing only = free), flushed once
// per block as bf16. fused_main measures ~5.9 TB/s ~ 93% of achievable.
__global__ __launch_bounds__(NTHR, 4) void fused_main(const float* __restrict__ logits,
                                                      const int* __restrict__ targets,
                                                      unsigned short* __restrict__ partial,
                                                      float* __restrict__ ce_blk) {
    __shared__ float colacc[C_COLS];
    __shared__ float zscr[2][16];
    __shared__ float xts[RPB];
    const int tid = threadIdx.x;
    const int blk = blockIdx.x;
    const bool tail = (tid < 832);   // j=7 group covers cols 28672..31999
    const size_t row0 = (size_t)blk * RPB;

    if (tid < RPB) {
        const int t = targets[row0 + tid];
        xts[tid] = logits[(row0 + tid) * (size_t)C_COLS + t];   // pre-gather x_target
    }
    for (int i = tid; i < C_COLS; i += NTHR) colacc[i] = 0.0f;
    __syncthreads();

    const float* rowbase = logits + row0 * (size_t)C_COLS;

    float4 cur[8], nxt[8];
    cur[7] = make_float4(0.f, 0.f, 0.f, 0.f);
    nxt[7] = make_float4(0.f, 0.f, 0.f, 0.f);
    float ce = 0.0f;

    // load row 0
    {
        const float* p = rowbase;
#pragma unroll
        for (int j = 0; j < 7; ++j)
            cur[j] = *reinterpret_cast<const float4*>(p + j * 4096 + 4 * tid);
        if (tail)
            cur[7] = *reinterpret_cast<const float4*>(p + 28672 + 4 * tid);
    }

    for (int r = 0; r < RPB; ++r) {
        // prefetch next row (hides under exp/reduce/accumulate)
        if (r + 1 < RPB) {
            const float* p = rowbase + (size_t)(r + 1) * C_COLS;
#pragma unroll
            for (int j = 0; j < 7; ++j)
                nxt[j] = *reinterpret_cast<const float4*>(p + j * 4096 + 4 * tid);
            if (tail)
                nxt[7] = *reinterpret_cast<const float4*>(p + 28672 + 4 * tid);
        }

        // in-place exp + thread-local Z
        float z = 0.0f;
#pragma unroll
        for (int j = 0; j < 7; ++j) {
            cur[j].x = __expf(cur[j].x);
            cur[j].y = __expf(cur[j].y);
            cur[j].z = __expf(cur[j].z);
            cur[j].w = __expf(cur[j].w);
            z += (cur[j].x + cur[j].y) + (cur[j].z + cur[j].w);
        }
        if (tail) {
            cur[7].x = __expf(cur[7].x);
            cur[7].y = __expf(cur[7].y);
            cur[7].z = __expf(cur[7].z);
            cur[7].w = __expf(cur[7].w);
            z += (cur[7].x + cur[7].y) + (cur[7].z + cur[7].w);
        }

        // block reduce Z -- SINGLE barrier (parity-buffered wave partials)
#pragma unroll
        for (int off = 1; off < 64; off <<= 1) z += __shfl_xor(z, off);
        if ((tid & 63) == 0) zscr[r & 1][tid >> 6] = z;
        __syncthreads();
        // every wave sums the 16 partials: 1 broadcast LDS read + 4 shuffles
        float zt = zscr[r & 1][tid & 15];
#pragma unroll
        for (int off = 1; off < 16; off <<= 1) zt += __shfl_xor(zt, off);
        const float rz = 1.0f / zt;
        if (tid == 0) ce += __logf(zt) - xts[r];   // CE fused, 1 thread

        // accumulate probs into LDS column accumulator (2-way banks only)
#pragma unroll
        for (int j = 0; j < 7; ++j) {
            const int base = j * 1024 + tid;
            colacc[base]         += cur[j].x * rz;
            colacc[base +  8000] += cur[j].y * rz;
            colacc[base + 16000] += cur[j].z * rz;
            colacc[base + 24000] += cur[j].w * rz;
        }
        if (tail) {
            const int base = 7 * 1024 + tid;
            colacc[base]         += cur[7].x * rz;
            colacc[base +  8000] += cur[7].y * rz;
            colacc[base + 16000] += cur[7].z * rz;
            colacc[base + 24000] += cur[7].w * rz;
        }

        if (r + 1 < RPB) {
#pragma unroll
            for (int j = 0; j < 8; ++j) cur[j] = nxt[j];
        }
    }

    // flush: un-swizzle LDS -> coalesced bf16 (ushort4) stores
    __syncthreads();
    unsigned short* mypart = partial + (size_t)blk * C_COLS;
    for (int c4 = tid; c4 < 8000; c4 += NTHR) {
        ushort4 v;
        v.x = f2bf(colacc[c4]);
        v.y = f2bf(colacc[c4 + 8000]);
        v.z = f2bf(colacc[c4 + 16000]);
        v.w = f2bf(colacc[c4 + 24000]);
        *reinterpret_cast<ushort4*>(mypart + 4 * c4) = v;
    }
    if (tid == 0) ce_blk[blk] = ce;
}

// 125 blocks x 1024 threads; block owns 256 columns [c0, c0+256).
// Builds its own LDS histogram of targets (replaces global counts + memset:
// exact integer counts, deterministic). Thread handles a column PAIR
// c = c0 + 2*(tid&127) via 4-byte ushort2 loads; k-chunk tid>>7
// (8 chunks x 32 partials each).
__global__ __launch_bounds__(NTHR) void mdca_reduce(const unsigned short* __restrict__ partial,
                                                    const int* __restrict__ targets,
                                                    float* __restrict__ pm) {
    __shared__ float2 sred[NTHR];
    __shared__ float sp[16];
    __shared__ int bins[256];
    const int tid = threadIdx.x;
    const int c0 = blockIdx.x * 256;

    if (tid < 256) bins[tid] = 0;
    __syncthreads();
    for (int i = tid; i < B_ROWS; i += NTHR) {
        const int t = targets[i] - c0;
        if ((unsigned)t < 256u) atomicAdd(&bins[t], 1);
    }

    const int cl = 2 * (tid & 127);
    const int c = c0 + cl;
    const int kc = tid >> 7;
    float s0 = 0.0f, s1 = 0.0f;
#pragma unroll 4
    for (int i = 0; i < 32; ++i) {
        const int k = kc * 32 + i;
        const unsigned int u =
            *reinterpret_cast<const unsigned int*>(partial + (size_t)k * C_COLS + c);
        s0 += __uint_as_float(u << 16);
        s1 += __uint_as_float(u & 0xffff0000u);
    }
    sred[tid] = make_float2(s0, s1);
    __syncthreads();   // covers bins + sred

    float d = 0.0f;
    if (tid < 128) {
        float t0 = 0.0f, t1 = 0.0f;
#pragma unroll
        for (int q = 0; q < 8; ++q) {
            const float2 v = sred[q * 128 + tid];
            t0 += v.x;
            t1 += v.y;
        }
        d = fabsf(t0 - (float)bins[cl]) + fabsf(t1 - (float)bins[cl + 1]);
    }
#pragma unroll
    for (int off = 1; off < 64; off <<= 1) d += __shfl_xor(d, off);
    if ((tid & 63) == 0) sp[tid >> 6] = d;
    __syncthreads();
    if (tid == 0) {
        float t = 0.0f;
#pragma unroll
        for (int w = 0; w < 16; ++w) t += sp[w];
        pm[blockIdx.x] = t;
    }
}

__global__ __launch_bounds__(256) void final_kernel(const float* __restrict__ ce_blk,
                                                    const float* __restrict__ pm,
                                                    float* __restrict__ out) {
    __shared__ float sp[4];
    const int tid = threadIdx.x;
    const float invB = 1.0f / B_ROWS;
    const float invBC = invB / C_COLS;
    float acc = ce_blk[tid] * invB;              // exactly 256 main blocks
    if (tid < 125) acc += pm[tid] * invBC;       // 125 reduce blocks
#pragma unroll
    for (int off = 1; off < 64; off <<= 1) acc += __shfl_xor(acc, off);
    if ((tid & 63) == 0) sp[tid >> 6] = acc;
    __syncthreads();
    if (tid == 0) out[0] = (sp[0] + sp[1]) + (sp[2] + sp[3]);
}

extern "C" void kernel_launch(void* const* d_in, const int* in_sizes, int n_in,
                              void* d_out, int out_size, void* d_ws, size_t ws_size,
                              hipStream_t stream) {
    const float* logits = (const float*)d_in[0];
    const int* targets  = (const int*)d_in[1];
    float* ws = (float*)d_ws;
    unsigned short* partial = (unsigned short*)d_ws;   // 256 x 32000 bf16
    float* ce_blk = ws + 4096000;
    float* pm     = ws + 4096256;

    fused_main<<<NBLK, NTHR, 0, stream>>>(logits, targets, partial, ce_blk);
    mdca_reduce<<<125, NTHR, 0, stream>>>(partial, targets, pm);
    final_kernel<<<1, 256, 0, stream>>>(ce_blk, pm, (float*)d_out);
}